// Round 11
// baseline (989.314 us; speedup 1.0000x reference)
//
#include <hip/hip_runtime.h>
#include <hip/hip_bf16.h>
#include <math.h>
#include <stdint.h>

#define Bn 16
#define Sn 512
#define Nn 321
#define Dn 512
#define DFn 2048
#define Pn 96
#define KP 352   // Nn padded to multiple of 32

typedef __bf16 bf16x8 __attribute__((ext_vector_type(8)));
typedef float f32x4 __attribute__((ext_vector_type(4)));
typedef __hip_bfloat16 bf16;

static __device__ __forceinline__ float gelu_exact(float x) {
    return 0.5f * x * (1.0f + erff(x * 0.7071067811865476f));
}

static __device__ __forceinline__ void gld16(const void* g, void* l) {
    __builtin_amdgcn_global_load_lds(
        (const __attribute__((address_space(1))) void*)(uintptr_t)g,
        (__attribute__((address_space(3))) void*)(uintptr_t)l, 16, 0, 0);
}

// ---------- fused fp32 -> bf16 weight conversion (single launch) ----------
struct CvtPack {
    const float* src[14];
    bf16* dst[14];
    int cnt[14];
};
__global__ void cvt_all_kernel(CvtPack p) {
    int seg = blockIdx.y;
    int n = p.cnt[seg];
    const float* s = p.src[seg];
    bf16* d = p.dst[seg];
    int i = (blockIdx.x * 256 + threadIdx.x) * 4;
    if (i + 3 < n) {
        float4 v = *reinterpret_cast<const float4*>(s + i);
        d[i] = __float2bfloat16(v.x);
        d[i + 1] = __float2bfloat16(v.y);
        d[i + 2] = __float2bfloat16(v.z);
        d[i + 3] = __float2bfloat16(v.w);
    }
}

// ---------- combined QKV bias: [l][0:512]=bq, [512:1024]=bk, [1024:1536]=bv ----------
__global__ void bias_pack_kernel(const float* __restrict__ bq, const float* __restrict__ bk,
                                 const float* __restrict__ bv, float* __restrict__ bqkv) {
    int idx = blockIdx.x * 256 + threadIdx.x;
    if (idx >= 3072) return;
    int l = idx / 1536, j = idx % 1536;
    float v = (j < 512) ? bq[l * 512 + j]
            : (j < 1024 ? bk[l * 512 + j - 512] : bv[l * 512 + j - 1024]);
    bqkv[idx] = v;
}

// ---------- per-(b,n) mean/std over S ----------
__global__ void stats_kernel(const float* __restrict__ x, float* __restrict__ means,
                             float* __restrict__ stdev) {
    int b = blockIdx.y;
    int n = blockIdx.x * 256 + threadIdx.x;
    if (n >= Nn) return;
    const float* p = x + (size_t)b * Sn * Nn + n;
    float s = 0.f, s2 = 0.f;
    for (int ss = 0; ss < Sn; ++ss) { float v = p[(size_t)ss * Nn]; s += v; s2 += v * v; }
    float mu = s * (1.0f / Sn);
    float var = s2 * (1.0f / Sn) - mu * mu;
    means[b * Nn + n] = mu;
    stdev[b * Nn + n] = sqrtf(var + 1e-5f);
}

// ---------- xT[b,n,s] = (x[b,s,n]-mu)/sd  (bf16 out) ----------
__global__ void transpose_norm_kernel(const float* __restrict__ x,
                                      const float* __restrict__ means,
                                      const float* __restrict__ stdev,
                                      bf16* __restrict__ xT) {
    __shared__ float tile[32][33];
    int b = blockIdx.z;
    int s0 = blockIdx.x * 32, n0 = blockIdx.y * 32;
    int tx = threadIdx.x, ty = threadIdx.y; // 32 x 8
#pragma unroll
    for (int u = 0; u < 4; ++u) {
        int srow = ty + u * 8;
        int n = n0 + tx;
        tile[srow][tx] = (n < Nn) ? x[((size_t)b * Sn + (s0 + srow)) * Nn + n] : 0.f;
    }
    __syncthreads();
#pragma unroll
    for (int u = 0; u < 4; ++u) {
        int n = n0 + ty + u * 8;
        int s = s0 + tx;
        if (n < Nn) {
            float mu = means[b * Nn + n], sd = stdev[b * Nn + n];
            xT[((size_t)b * Nn + n) * Sn + s] = __float2bfloat16((tile[tx][ty + u * 8] - mu) / sd);
        }
    }
}

// ---------- bf16 MFMA GEMM: dbuf global_load_lds + XCD swizzle ----------
// DUAL=1: cols >=1024 go to C2 (bf16, ld 512), cols <1024 to C (ld 1024).
template <int OUT, int EPI, int DUAL>
__global__ __launch_bounds__(256) void mm_kernel(
    const bf16* __restrict__ A, const bf16* __restrict__ Bm,
    const float* __restrict__ bias, void* __restrict__ C, void* __restrict__ C2,
    int Mdim, int Ndim, int Kdim, int lda, int ldb, int ldc,
    long sAi, long sAo, long sBi, long sBo, long sCi, long sCo, int innerB) {
    int z = blockIdx.z;
    int zi = z % innerB, zo = z / innerB;
    const bf16* Ab = A + (size_t)zi * sAi + (size_t)zo * sAo;
    const bf16* Bb = Bm + (size_t)zi * sBi + (size_t)zo * sBo;

    // XCD-grouping swizzle: blocks sharing a C row-tile land on the same XCD.
    int gx = gridDim.x, gy = gridDim.y;
    int lin = blockIdx.y * gx + blockIdx.x;
    int prefix = (gy & ~7) * gx;
    int bx, by;
    if (lin < prefix) {
        bx = (lin >> 3) % gx;
        by = (lin / (8 * gx)) * 8 + (lin & 7);
    } else {
        int r = lin - prefix;
        bx = r % gx;
        by = (gy & ~7) + r / gx;
    }

    __shared__ __align__(16) bf16 As[2][128 * 32];
    __shared__ __align__(16) bf16 Bs[2][128 * 32];
    int t = threadIdx.x;
    int wave = t >> 6, lane = t & 63;
    int wr = wave >> 1, wc = wave & 1;
    int q = lane >> 4, l16 = lane & 15;
    int i0 = by * 128, j0 = bx * 128;

    int srow0 = t >> 2;              // + u*64
    int scol = (t & 3) * 8;          // LDS col base (element units)
    f32x4 acc[4][4] = {};

    int nIter = Kdim >> 5;

    auto stage = [&](int k0, int buf) {
#pragma unroll
        for (int u = 0; u < 2; ++u) {
            int row = u * 64 + srow0;
            int gcol = scol ^ (((row >> 1) & 3) << 3);
            int gi = i0 + row; if (gi >= Mdim) gi = Mdim - 1;
            gld16(Ab + (size_t)gi * lda + k0 + gcol, &As[buf][u * 2048 + wave * 512]);
            int gj = j0 + row; if (gj >= Ndim) gj = Ndim - 1;
            gld16(Bb + (size_t)gj * ldb + k0 + gcol, &Bs[buf][u * 2048 + wave * 512]);
        }
    };

    stage(0, 0);
    for (int it = 0; it < nIter; ++it) {
        __syncthreads();                       // drains stage(it) loads
        if (it + 1 < nIter) stage((it + 1) << 5, (it + 1) & 1);  // overlaps compute below
        int buf = it & 1;
        bf16x8 af[4], bfr[4];
#pragma unroll
        for (int mi = 0; mi < 4; ++mi) {
            int r = wr * 64 + mi * 16 + l16;
            int cl = (q * 8) ^ (((r >> 1) & 3) << 3);
            af[mi] = *reinterpret_cast<const bf16x8*>(&As[buf][r * 32 + cl]);
        }
#pragma unroll
        for (int ni = 0; ni < 4; ++ni) {
            int r = wc * 64 + ni * 16 + l16;
            int cl = (q * 8) ^ (((r >> 1) & 3) << 3);
            bfr[ni] = *reinterpret_cast<const bf16x8*>(&Bs[buf][r * 32 + cl]);
        }
#pragma unroll
        for (int mi = 0; mi < 4; ++mi)
#pragma unroll
            for (int ni = 0; ni < 4; ++ni)
                acc[mi][ni] = __builtin_amdgcn_mfma_f32_16x16x32_bf16(af[mi], bfr[ni], acc[mi][ni], 0, 0, 0);
    }
    size_t cbase = (size_t)zi * sCi + (size_t)zo * sCo;
#pragma unroll
    for (int mi = 0; mi < 4; ++mi) {
#pragma unroll
        for (int r = 0; r < 4; ++r) {
            int gi = i0 + wr * 64 + mi * 16 + q * 4 + r;
            if (gi >= Mdim) continue;
#pragma unroll
            for (int ni = 0; ni < 4; ++ni) {
                int gj = j0 + wc * 64 + ni * 16 + l16;
                if (gj >= Ndim) continue;
                float v = acc[mi][ni][r];
                if (bias) v += bias[gj];
                if (EPI == 1) v = gelu_exact(v);
                if (DUAL && gj >= 1024) {
                    ((bf16*)C2)[(size_t)gi * 512 + (gj - 1024)] = __float2bfloat16(v);
                } else {
                    size_t cidx = cbase + (size_t)gi * ldc + gj;
                    if (OUT == 0) ((float*)C)[cidx] = v;
                    else ((bf16*)C)[cidx] = __float2bfloat16(v);
                }
            }
        }
    }
}

// ---------- SWT decomposition: h = A [+ A2] (fp32) -> coeffs bf16; optional h writeback ----------
__global__ __launch_bounds__(128) void swt_dec_kernel(
    const float* __restrict__ h, const float* __restrict__ h2, float* __restrict__ hout,
    const float* __restrict__ h0f, const float* __restrict__ h1f, bf16* __restrict__ coeffs) {
    __shared__ float a[2][512];
    int b = blockIdx.y, n = blockIdx.x, t = threadIdx.x;
    size_t roff = ((size_t)b * Nn + n) * Dn;
    const float* hrow = h + roff;
#pragma unroll
    for (int u = 0; u < 4; ++u) {
        float v = hrow[t + u * 128];
        if (h2) v += h2[roff + t + u * 128];
        a[0][t + u * 128] = v;
        if (hout) hout[roff + t + u * 128] = v;
    }
    float f0[3], f1[3];
#pragma unroll
    for (int k = 0; k < 3; ++k) { f0[k] = h0f[n * 3 + k]; f1[k] = h1f[n * 3 + k]; }
    __syncthreads();
    bf16* cb = coeffs + roff * 4;
    int cur = 0;
    for (int lev = 0; lev < 3; ++lev) {
        int dil = 1 << lev;
        int pl = 2 * dil - (3 * dil) / 2; // 1,1,2
#pragma unroll
        for (int u = 0; u < 4; ++u) {
            int d = t + u * 128;
            float dv = 0.f, av = 0.f;
#pragma unroll
            for (int k = 0; k < 3; ++k) {
                int idx = (d + k * dil - pl) & 511;
                float xv = a[cur][idx];
                dv += f1[k] * xv;
                av += f0[k] * xv;
            }
            cb[(size_t)(3 - lev) * Dn + d] = __float2bfloat16(dv);
            a[cur ^ 1][d] = av;
        }
        __syncthreads();
        cur ^= 1;
    }
#pragma unroll
    for (int u = 0; u < 4; ++u) cb[t + u * 128] = __float2bfloat16(a[cur][t + u * 128]);
}

// ---------- SWT reconstruction: attn(b,m,n,:) bf16 -> rec(b,n,:) bf16 ----------
__global__ __launch_bounds__(128) void swt_rec_kernel(
    const bf16* __restrict__ attn, const float* __restrict__ g0f,
    const float* __restrict__ g1f, bf16* __restrict__ rec) {
    __shared__ float a[2][512];
    __shared__ float det[512];
    int b = blockIdx.y, n = blockIdx.x, t = threadIdx.x;
    const bf16* base = attn + ((size_t)(b * 4) * Nn + n) * Dn;
#pragma unroll
    for (int u = 0; u < 4; ++u) a[0][t + u * 128] = __bfloat162float(base[t + u * 128]);
    float w0[3], w1[3];
#pragma unroll
    for (int k = 0; k < 3; ++k) { w0[k] = g0f[n * 3 + k]; w1[k] = g1f[n * 3 + k]; }
    int cur = 0;
    for (int i = 0; i < 3; ++i) {
        int dil = 4 >> i;
        int pl = (3 * dil) / 2; // 6,3,1
        const bf16* drow = base + (size_t)(1 + i) * Nn * Dn;
#pragma unroll
        for (int u = 0; u < 4; ++u) det[t + u * 128] = __bfloat162float(drow[t + u * 128]);
        __syncthreads();
#pragma unroll
        for (int u = 0; u < 4; ++u) {
            int d = t + u * 128;
            float s = 0.f;
#pragma unroll
            for (int k = 0; k < 3; ++k) {
                int idx = (d + k * dil - pl) & 511;
                s += w0[k] * a[cur][idx] + w1[k] * det[idx];
            }
            a[cur ^ 1][d] = s * 0.5f;
        }
        __syncthreads();
        cur ^= 1;
    }
    bf16* out = rec + ((size_t)b * Nn + n) * Dn;
#pragma unroll
    for (int u = 0; u < 4; ++u) out[t + u * 128] = __float2bfloat16(a[cur][t + u * 128]);
}

// ---------- fused transpose-convert for QK: (b,n,m,[qk]e) -> (qk,b,m,e,n-pad) ----------
__global__ void tconv2_kernel(const bf16* __restrict__ QK, bf16* __restrict__ QtKt) {
    __shared__ bf16 tile[32][33];
    int zz = blockIdx.z;           // 0..127
    int qk = zz >> 6, bm = zz & 63;
    int b = bm >> 2, m = bm & 3;
    int e0 = blockIdx.x * 32, n0 = blockIdx.y * 32;
    int tx = threadIdx.x, ty = threadIdx.y; // 32 x 8
    const bf16* ib = QK + (size_t)b * Nn * 4096 + (size_t)m * 1024 + (size_t)qk * 512;
    bf16* ob = QtKt + (size_t)qk * 64 * 512 * KP + (size_t)bm * 512 * KP;
#pragma unroll
    for (int u = 0; u < 4; ++u) {
        int n = n0 + ty + u * 8;
        bf16 v = __float2bfloat16(0.f);
        if (n < Nn) v = ib[(size_t)n * 4096 + e0 + tx];
        tile[ty + u * 8][tx] = v;
    }
    __syncthreads();
#pragma unroll
    for (int u = 0; u < 4; ++u) {
        int e = e0 + ty + u * 8;
        int n = n0 + tx;
        if (n < KP) ob[(size_t)e * KP + n] = tile[tx][ty + u * 8];
    }
}

// ---------- column sum-sq from transposed QtKt rows (contiguous) ----------
__global__ __launch_bounds__(256) void colsq_t_kernel(const bf16* __restrict__ QtKt,
                                                      float* __restrict__ outv) {
    int wave = threadIdx.x >> 6, lane = threadIdx.x & 63;
    size_t row = (size_t)blockIdx.x * 4 + wave;   // 0..65535
    const bf16* p = QtKt + row * KP;
    float s = 0.f;
#pragma unroll
    for (int j = 0; j < 6; ++j) {
        int idx = lane + j * 64;
        if (idx < KP) { float v = __bfloat162float(p[idx]); s += v * v; }
    }
#pragma unroll
    for (int m = 1; m < 64; m <<= 1) s += __shfl_xor(s, m);
    if (lane == 0) outv[row] = s;
}

// ---------- geometric scores + softmax, wave-per-row, in place ----------
__global__ __launch_bounds__(256) void wedge_softmax_kernel(
    bf16* __restrict__ Smat, const float* __restrict__ qn2, const float* __restrict__ kn2) {
    int wave = threadIdx.x >> 6, lane = threadIdx.x & 63;
    int rowid = blockIdx.x * 4 + wave;            // 0..32767
    int bm = rowid >> 9, l = rowid & 511;
    bf16* row = Smat + (size_t)rowid * 512;
    const float* kn = kn2 + (size_t)bm * 512;
    float q2 = qn2[(size_t)bm * 512 + l];
    const float scale = rsqrtf(321.0f);
    bf16x8 dv = *reinterpret_cast<const bf16x8*>(row + lane * 8);
    float kk[8];
    *reinterpret_cast<float4*>(&kk[0]) = *reinterpret_cast<const float4*>(kn + lane * 8);
    *reinterpret_cast<float4*>(&kk[4]) = *reinterpret_cast<const float4*>(kn + lane * 8 + 4);
    float sc[8];
    float mx = -1e30f;
#pragma unroll
    for (int j = 0; j < 8; ++j) {
        float d = (float)dv[j];
        float w = sqrtf(fmaxf(q2 * kk[j] - d * d, 0.f) + 1e-8f);
        sc[j] = (0.7f * d + 0.3f * w) * scale;
        mx = fmaxf(mx, sc[j]);
    }
#pragma unroll
    for (int m = 1; m < 64; m <<= 1) mx = fmaxf(mx, __shfl_xor(mx, m));
    float sum = 0.f;
#pragma unroll
    for (int j = 0; j < 8; ++j) { sc[j] = expf(sc[j] - mx); sum += sc[j]; }
#pragma unroll
    for (int m = 1; m < 64; m <<= 1) sum += __shfl_xor(sum, m);
    float inv = 1.0f / sum;
    bf16x8 o;
#pragma unroll
    for (int j = 0; j < 8; ++j) o[j] = (__bf16)(sc[j] * inv);
    *reinterpret_cast<bf16x8*>(row + lane * 8) = o;
}

// ---------- LayerNorm, wave-per-row (grid = R/4, block 256) ----------
__global__ __launch_bounds__(256) void ln_kernel(
    const float* __restrict__ A, const float* __restrict__ R, const float* __restrict__ R2,
    const float* __restrict__ g, const float* __restrict__ bb,
    float* __restrict__ outf, bf16* __restrict__ outb) {
    int wave = threadIdx.x >> 6, lane = threadIdx.x & 63;
    size_t r = (size_t)blockIdx.x * 4 + wave;
    const float* ra = A + r * Dn + lane * 8;
    float x[8];
    *reinterpret_cast<float4*>(&x[0]) = *reinterpret_cast<const float4*>(ra);
    *reinterpret_cast<float4*>(&x[4]) = *reinterpret_cast<const float4*>(ra + 4);
    if (R) {
        const float* rr = R + r * Dn + lane * 8;
        float y[8];
        *reinterpret_cast<float4*>(&y[0]) = *reinterpret_cast<const float4*>(rr);
        *reinterpret_cast<float4*>(&y[4]) = *reinterpret_cast<const float4*>(rr + 4);
#pragma unroll
        for (int j = 0; j < 8; ++j) x[j] += y[j];
    }
    if (R2) {
        const float* rr = R2 + r * Dn + lane * 8;
        float y[8];
        *reinterpret_cast<float4*>(&y[0]) = *reinterpret_cast<const float4*>(rr);
        *reinterpret_cast<float4*>(&y[4]) = *reinterpret_cast<const float4*>(rr + 4);
#pragma unroll
        for (int j = 0; j < 8; ++j) x[j] += y[j];
    }
    float s = 0.f, s2 = 0.f;
#pragma unroll
    for (int j = 0; j < 8; ++j) { s += x[j]; s2 += x[j] * x[j]; }
#pragma unroll
    for (int m = 1; m < 64; m <<= 1) { s += __shfl_xor(s, m); s2 += __shfl_xor(s2, m); }
    float mean = s * (1.0f / Dn);
    float var = s2 * (1.0f / Dn) - mean * mean;
    float inv = rsqrtf(var + 1e-5f);
#pragma unroll
    for (int j = 0; j < 8; ++j) {
        int d = lane * 8 + j;
        float v = (x[j] - mean) * inv * g[d] + bb[d];
        if (outf) outf[r * Dn + d] = v;
        if (outb) outb[r * Dn + d] = __float2bfloat16(v);
    }
}

// ---------- dec[b,p,n] = (sum of 4 split-K partials)*sd + mu ----------
__global__ void out_scale_kernel(const float* __restrict__ ptmp,
                                 const float* __restrict__ means,
                                 const float* __restrict__ stdev, float* __restrict__ dec) {
    int idx = blockIdx.x * 256 + threadIdx.x;
    if (idx >= Bn * Pn * Nn) return;
    int n = idx % Nn;
    int bp = idx / Nn;
    int p = bp % Pn;
    int b = bp / Pn;
    const size_t PS = (size_t)Bn * Nn * Pn;
    size_t base = ((size_t)b * Nn + n) * Pn + p;
    float v = ptmp[base] + ptmp[base + PS] + ptmp[base + 2 * PS] + ptmp[base + 3 * PS];
    dec[idx] = v * stdev[b * Nn + n] + means[b * Nn + n];
}

extern "C" void kernel_launch(void* const* d_in, const int* in_sizes, int n_in,
                              void* d_out, int out_size, void* d_ws, size_t ws_size,
                              hipStream_t stream) {
    const float* x_enc = (const float*)d_in[0];
    const float* emb_W = (const float*)d_in[1];
    const float* emb_b = (const float*)d_in[2];
    const float* h0 = (const float*)d_in[3];
    const float* h1 = (const float*)d_in[4];
    const float* g0 = (const float*)d_in[5];
    const float* g1 = (const float*)d_in[6];
    const float* Wq = (const float*)d_in[7];
    const float* bq = (const float*)d_in[8];
    const float* Wk = (const float*)d_in[9];
    const float* bk = (const float*)d_in[10];
    const float* Wv = (const float*)d_in[11];
    const float* bv = (const float*)d_in[12];
    const float* Wo = (const float*)d_in[13];
    const float* bo = (const float*)d_in[14];
    const float* W1 = (const float*)d_in[15];
    const float* b1 = (const float*)d_in[16];
    const float* W2 = (const float*)d_in[17];
    const float* b2 = (const float*)d_in[18];
    const float* ln1_g = (const float*)d_in[19];
    const float* ln1_b = (const float*)d_in[20];
    const float* ln2_g = (const float*)d_in[21];
    const float* ln2_b = (const float*)d_in[22];
    const float* lnf_g = (const float*)d_in[23];
    const float* lnf_b = (const float*)d_in[24];
    const float* proj_W = (const float*)d_in[25];
    const float* proj_b = (const float*)d_in[26];

    float* dec = (float*)d_out;
    float* means = dec + (size_t)Bn * Pn * Nn;
    float* stdev = means + (size_t)Bn * Nn;

    // ---- workspace carve (~154 MB, proven watermark) ----
    char* p = (char*)d_ws;
    auto alloc = [&](size_t bytes) { char* r = p; p += (bytes + 255) & ~(size_t)255; return r; };
    const size_t RD = (size_t)Bn * Nn * Dn;        // 2,629,632 elements
    const size_t RQ4 = RD * 4;                     // 10,518,528

    bf16* embWb = (bf16*)alloc(262144 * 2);
    bf16* Wqkvb = (bf16*)alloc(2 * 786432 * 2);    // per layer: [Wq;Wk;Wv] rows, 1536x512
    bf16* Wob = (bf16*)alloc(2 * 262144 * 2);
    bf16* W1b = (bf16*)alloc(2 * 1048576 * 2);
    bf16* W2b = (bf16*)alloc(2 * 1048576 * 2);
    bf16* projWb = (bf16*)alloc(49152 * 2);
    float* bqkv = (float*)alloc(3072 * 4);

    float* hbuf = (float*)alloc(RD * 4);
    char* regC = alloc(RQ4 * 2);                     // coeffs_b | attn_b
    char* regQ = alloc(RQ4 * 2);                     // QK0b(head) | Smat(head) | recb,x1b | ptmp
    char* regK = alloc(RQ4 * 2);                     // QK0b(tail) | Smat(tail)
    char* regV = alloc(RQ4 * 2);                     // V0b | yb
    char* regT = alloc((size_t)2 * 64 * 512 * KP * 2); // xT_b | QtKt | x1,tmp(x2),hfb
    float* qn2 = (float*)alloc((size_t)2 * 64 * 512 * 4);
    float* kn2 = qn2 + 32768;

    bf16* coeffs_b = (bf16*)regC;
    bf16* attn_b = (bf16*)regC;
    bf16* QK0b = (bf16*)regQ;                        // 20544 x 1024, spans regQ+regK
    bf16* Smat = (bf16*)regQ;
    bf16* recb = (bf16*)regQ;
    bf16* x1b = (bf16*)(regQ + RD * 2);
    float* ptmp = (float*)regQ;
    bf16* V0b = (bf16*)regV;                         // 20544 x 512
    bf16* yb = (bf16*)regV;
    bf16* QtKt = (bf16*)regT;
    bf16* Qt = QtKt;
    bf16* Kt = QtKt + (size_t)64 * 512 * KP;
    bf16* xT_b = (bf16*)regT;
    float* x1 = (float*)regT;
    float* tmp = (float*)(regT + RD * 4);            // 2 partials fp32 (also embed partials)
    bf16* hfb = (bf16*)(regT + RD * 12);

    const int R = Bn * Nn;   // 5136
    const int RQr = R * 4;   // 20544
    const long sbm = (long)4 * Nn * 512;
    const long sS = (long)512 * 512;
    const long sTq = (long)512 * KP;
    const long sTb = 4 * sTq;

    CvtPack cp;
    int ci = 0;
    auto addcvt = [&](const float* s, bf16* d, int n) { cp.src[ci] = s; cp.dst[ci] = d; cp.cnt[ci] = n; ++ci; };
    addcvt(emb_W, embWb, 262144);
    for (int l = 0; l < 2; ++l) {
        addcvt(Wq + (size_t)l * 262144, Wqkvb + (size_t)l * 786432, 262144);
        addcvt(Wk + (size_t)l * 262144, Wqkvb + (size_t)l * 786432 + 262144, 262144);
        addcvt(Wv + (size_t)l * 262144, Wqkvb + (size_t)l * 786432 + 524288, 262144);
        addcvt(Wo + (size_t)l * 262144, Wob + (size_t)l * 262144, 262144);
        addcvt(W1 + (size_t)l * 1048576, W1b + (size_t)l * 1048576, 1048576);
        addcvt(W2 + (size_t)l * 1048576, W2b + (size_t)l * 1048576, 1048576);
    }
    addcvt(proj_W, projWb, 49152);
    cvt_all_kernel<<<dim3(1048576 / 4 / 256, 14), 256, 0, stream>>>(cp);
    bias_pack_kernel<<<12, 256, 0, stream>>>(bq, bk, bv, bqkv);

    stats_kernel<<<dim3((Nn + 255) / 256, Bn), 256, 0, stream>>>(x_enc, means, stdev);
    transpose_norm_kernel<<<dim3(Sn / 32, (Nn + 31) / 32, Bn), dim3(32, 8), 0, stream>>>(
        x_enc, means, stdev, xT_b);

    // embed split-K=2: partials -> tmp, tmp+RD (summed inside layer-0 swt_dec)
    mm_kernel<0, 0, 0><<<dim3(4, (R + 127) / 128, 2), 256, 0, stream>>>(
        xT_b, embWb, emb_b, tmp, nullptr, R, Dn, 256, Sn, Sn, Dn,
        256, 0, 256, 0, (long)RD, 0, 2);

    for (int l = 0; l < 2; ++l) {
        const float* h0l = h0 + (size_t)l * Nn * 3;
        const float* h1l = h1 + (size_t)l * Nn * 3;
        const float* g0l = g0 + (size_t)l * Nn * 3;
        const float* g1l = g1 + (size_t)l * Nn * 3;

        if (l == 0)
            swt_dec_kernel<<<dim3(Nn, Bn), 128, 0, stream>>>(tmp, tmp + RD, hbuf, h0l, h1l, coeffs_b);
        else
            swt_dec_kernel<<<dim3(Nn, Bn), 128, 0, stream>>>(hbuf, nullptr, nullptr, h0l, h1l, coeffs_b);

        // fused QKV: rows (b,n,m) x 1536; cols<1024 -> QK0b (ld 1024), cols>=1024 -> V0b (ld 512)
        mm_kernel<1, 0, 1><<<dim3(12, (RQr + 127) / 128, 1), 256, 0, stream>>>(
            coeffs_b, Wqkvb + (size_t)l * 786432, bqkv + (size_t)l * 1536, QK0b, V0b,
            RQr, 1536, Dn, Dn, Dn, 1024, 0, 0, 0, 0, 0, 0, 1);

        tconv2_kernel<<<dim3(16, 11, 128), dim3(32, 8), 0, stream>>>(QK0b, QtKt);
        colsq_t_kernel<<<16384, 256, 0, stream>>>(QtKt, qn2);

        // dot[bm,l,s] = sum_n Qt[l,n]*Kt[s,n] -> bf16 Smat (QK0b dead now)
        mm_kernel<1, 0, 0><<<dim3(4, 4, 64), 256, 0, stream>>>(
            Qt, Kt, nullptr, Smat, nullptr, 512, 512, KP, KP, KP, 512,
            sTq, sTb, sTq, sTb, sS, 4 * sS, 4);

        wedge_softmax_kernel<<<8192, 256, 0, stream>>>(Smat, qn2, kn2);

        // attn[b,m,n,l] = sum_s V0b[(b,n,m),s] * Smat[bm,l,s] -> bf16
        mm_kernel<1, 0, 0><<<dim3(4, (Nn + 127) / 128, 64), 256, 0, stream>>>(
            V0b, Smat, nullptr, attn_b, nullptr, Nn, 512, 512, 2048, 512, 512,
            512, sbm, sS, 4 * sS, (long)Nn * 512, (long)4 * Nn * 512, 4);

        // Smat dead; recb overwrites its head
        swt_rec_kernel<<<dim3(Nn, Bn), 128, 0, stream>>>(attn_b, g0l, g1l, recb);

        // Wo split-K=2 -> tmp partials
        mm_kernel<0, 0, 0><<<dim3(4, (R + 127) / 128, 2), 256, 0, stream>>>(
            recb, Wob + (size_t)l * 262144, bo + (size_t)l * Dn, tmp, nullptr,
            R, Dn, 256, Dn, Dn, Dn, 256, 0, 256, 0, (long)RD, 0, 2);
        ln_kernel<<<R / 4, 256, 0, stream>>>(hbuf, tmp, tmp + RD, ln1_g + (size_t)l * Dn,
                                             ln1_b + (size_t)l * Dn, x1, x1b);

        // FFN1 (gelu, bf16 out)
        mm_kernel<1, 1, 0><<<dim3(16, (R + 127) / 128, 1), 256, 0, stream>>>(
            x1b, W1b + (size_t)l * 1048576, b1 + (size_t)l * DFn, yb, nullptr,
            R, DFn, Dn, Dn, Dn, DFn, 0, 0, 0, 0, 0, 0, 1);
        // FFN2 split-K=2 -> tmp partials
        mm_kernel<0, 0, 0><<<dim3(4, (R + 127) / 128, 2), 256, 0, stream>>>(
            yb, W2b + (size_t)l * 1048576, b2 + (size_t)l * Dn, tmp, nullptr,
            R, Dn, 1024, DFn, DFn, Dn, 1024, 0, 1024, 0, (long)RD, 0, 2);
        ln_kernel<<<R / 4, 256, 0, stream>>>(x1, tmp, tmp + RD, ln2_g + (size_t)l * Dn,
                                             ln2_b + (size_t)l * Dn, hbuf, nullptr);
    }

    ln_kernel<<<R / 4, 256, 0, stream>>>(hbuf, nullptr, nullptr, lnf_g, lnf_b, nullptr, hfb);
    // proj split-K=4 -> ptmp partials
    mm_kernel<0, 0, 0><<<dim3(1, (R + 127) / 128, 4), 256, 0, stream>>>(
        hfb, projWb, proj_b, ptmp, nullptr, R, Pn, 128, Dn, Dn, Pn,
        128, 0, 128, 0, (long)R * Pn, 0, 4);
    out_scale_kernel<<<(Bn * Pn * Nn + 255) / 256, 256, 0, stream>>>(ptmp, means, stdev, dec);
}

// Round 12
// 902.493 us; speedup vs baseline: 1.0962x; 1.0962x over previous
//
#include <hip/hip_runtime.h>
#include <hip/hip_bf16.h>
#include <math.h>
#include <stdint.h>

#define Bn 16
#define Sn 512
#define Nn 321
#define Dn 512
#define DFn 2048
#define Pn 96
#define KP 352   // Nn padded to multiple of 32

typedef __bf16 bf16x8 __attribute__((ext_vector_type(8)));
typedef float f32x4 __attribute__((ext_vector_type(4)));
typedef __hip_bfloat16 bf16;

static __device__ __forceinline__ float gelu_exact(float x) {
    return 0.5f * x * (1.0f + erff(x * 0.7071067811865476f));
}

static __device__ __forceinline__ void gld16(const void* g, void* l) {
    __builtin_amdgcn_global_load_lds(
        (const __attribute__((address_space(1))) void*)(uintptr_t)g,
        (__attribute__((address_space(3))) void*)(uintptr_t)l, 16, 0, 0);
}

// ---------- fused fp32 -> bf16 weight conversion (single launch) ----------
struct CvtPack {
    const float* src[14];
    bf16* dst[14];
    int cnt[14];
};
__global__ void cvt_all_kernel(CvtPack p) {
    int seg = blockIdx.y;
    int n = p.cnt[seg];
    const float* s = p.src[seg];
    bf16* d = p.dst[seg];
    int i = (blockIdx.x * 256 + threadIdx.x) * 4;
    if (i + 3 < n) {
        float4 v = *reinterpret_cast<const float4*>(s + i);
        d[i] = __float2bfloat16(v.x);
        d[i + 1] = __float2bfloat16(v.y);
        d[i + 2] = __float2bfloat16(v.z);
        d[i + 3] = __float2bfloat16(v.w);
    }
}

// ---------- combined QK bias ----------
__global__ void bias_pack_kernel(const float* __restrict__ bq, const float* __restrict__ bk,
                                 float* __restrict__ bqk) {
    int idx = blockIdx.x * 256 + threadIdx.x;
    if (idx >= 2048) return;
    int l = idx >> 10, j = idx & 1023;
    bqk[idx] = (j < 512) ? bq[l * 512 + j] : bk[l * 512 + j - 512];
}

// ---------- per-(b,n) mean/std over S ----------
__global__ void stats_kernel(const float* __restrict__ x, float* __restrict__ means,
                             float* __restrict__ stdev) {
    int b = blockIdx.y;
    int n = blockIdx.x * 256 + threadIdx.x;
    if (n >= Nn) return;
    const float* p = x + (size_t)b * Sn * Nn + n;
    float s = 0.f, s2 = 0.f;
    for (int ss = 0; ss < Sn; ++ss) { float v = p[(size_t)ss * Nn]; s += v; s2 += v * v; }
    float mu = s * (1.0f / Sn);
    float var = s2 * (1.0f / Sn) - mu * mu;
    means[b * Nn + n] = mu;
    stdev[b * Nn + n] = sqrtf(var + 1e-5f);
}

// ---------- xT[b,n,s] = (x[b,s,n]-mu)/sd  (bf16 out) ----------
__global__ void transpose_norm_kernel(const float* __restrict__ x,
                                      const float* __restrict__ means,
                                      const float* __restrict__ stdev,
                                      bf16* __restrict__ xT) {
    __shared__ float tile[32][33];
    int b = blockIdx.z;
    int s0 = blockIdx.x * 32, n0 = blockIdx.y * 32;
    int tx = threadIdx.x, ty = threadIdx.y; // 32 x 8
#pragma unroll
    for (int u = 0; u < 4; ++u) {
        int srow = ty + u * 8;
        int n = n0 + tx;
        tile[srow][tx] = (n < Nn) ? x[((size_t)b * Sn + (s0 + srow)) * Nn + n] : 0.f;
    }
    __syncthreads();
#pragma unroll
    for (int u = 0; u < 4; ++u) {
        int n = n0 + ty + u * 8;
        int s = s0 + tx;
        if (n < Nn) {
            float mu = means[b * Nn + n], sd = stdev[b * Nn + n];
            xT[((size_t)b * Nn + n) * Sn + s] = __float2bfloat16((tile[tx][ty + u * 8] - mu) / sd);
        }
    }
}

// ---------- bf16 MFMA GEMM (round-8/10 proven): dbuf global_load_lds + XCD swizzle ----------
template <int OUT, int EPI>
__global__ __launch_bounds__(256) void mm_kernel(
    const bf16* __restrict__ A, const bf16* __restrict__ Bm,
    const float* __restrict__ bias, void* __restrict__ C,
    int Mdim, int Ndim, int Kdim, int lda, int ldb, int ldc,
    long sAi, long sAo, long sBi, long sBo, long sCi, long sCo, int innerB) {
    int z = blockIdx.z;
    int zi = z % innerB, zo = z / innerB;
    const bf16* Ab = A + (size_t)zi * sAi + (size_t)zo * sAo;
    const bf16* Bb = Bm + (size_t)zi * sBi + (size_t)zo * sBo;

    // XCD-grouping swizzle: blocks sharing a C row-tile land on the same XCD.
    int gx = gridDim.x, gy = gridDim.y;
    int lin = blockIdx.y * gx + blockIdx.x;
    int prefix = (gy & ~7) * gx;
    int bx, by;
    if (lin < prefix) {
        bx = (lin >> 3) % gx;
        by = (lin / (8 * gx)) * 8 + (lin & 7);
    } else {
        int r = lin - prefix;
        bx = r % gx;
        by = (gy & ~7) + r / gx;
    }

    __shared__ __align__(16) bf16 As[2][128 * 32];
    __shared__ __align__(16) bf16 Bs[2][128 * 32];
    int t = threadIdx.x;
    int wave = t >> 6, lane = t & 63;
    int wr = wave >> 1, wc = wave & 1;
    int q = lane >> 4, l16 = lane & 15;
    int i0 = by * 128, j0 = bx * 128;

    int srow0 = t >> 2;              // + u*64
    int scol = (t & 3) * 8;          // LDS col base (element units)
    f32x4 acc[4][4] = {};

    int nIter = Kdim >> 5;

    auto stage = [&](int k0, int buf) {
#pragma unroll
        for (int u = 0; u < 2; ++u) {
            int row = u * 64 + srow0;
            int gcol = scol ^ (((row >> 1) & 3) << 3);
            int gi = i0 + row; if (gi >= Mdim) gi = Mdim - 1;
            gld16(Ab + (size_t)gi * lda + k0 + gcol, &As[buf][u * 2048 + wave * 512]);
            int gj = j0 + row; if (gj >= Ndim) gj = Ndim - 1;
            gld16(Bb + (size_t)gj * ldb + k0 + gcol, &Bs[buf][u * 2048 + wave * 512]);
        }
    };

    stage(0, 0);
    for (int it = 0; it < nIter; ++it) {
        __syncthreads();                       // drains stage(it) loads
        if (it + 1 < nIter) stage((it + 1) << 5, (it + 1) & 1);  // overlaps compute below
        int buf = it & 1;
        bf16x8 af[4], bfr[4];
#pragma unroll
        for (int mi = 0; mi < 4; ++mi) {
            int r = wr * 64 + mi * 16 + l16;
            int cl = (q * 8) ^ (((r >> 1) & 3) << 3);
            af[mi] = *reinterpret_cast<const bf16x8*>(&As[buf][r * 32 + cl]);
        }
#pragma unroll
        for (int ni = 0; ni < 4; ++ni) {
            int r = wc * 64 + ni * 16 + l16;
            int cl = (q * 8) ^ (((r >> 1) & 3) << 3);
            bfr[ni] = *reinterpret_cast<const bf16x8*>(&Bs[buf][r * 32 + cl]);
        }
#pragma unroll
        for (int mi = 0; mi < 4; ++mi)
#pragma unroll
            for (int ni = 0; ni < 4; ++ni)
                acc[mi][ni] = __builtin_amdgcn_mfma_f32_16x16x32_bf16(af[mi], bfr[ni], acc[mi][ni], 0, 0, 0);
    }
    size_t cbase = (size_t)zi * sCi + (size_t)zo * sCo;
    const float* bs = (bias && zi == 0) ? bias : nullptr;  // split-K: bias once
    if (bias && innerB > 1 && sCi == 0) bs = bias;          // (batch mode keeps bias)
#pragma unroll
    for (int mi = 0; mi < 4; ++mi) {
#pragma unroll
        for (int r = 0; r < 4; ++r) {
            int gi = i0 + wr * 64 + mi * 16 + q * 4 + r;
            if (gi >= Mdim) continue;
#pragma unroll
            for (int ni = 0; ni < 4; ++ni) {
                int gj = j0 + wc * 64 + ni * 16 + l16;
                if (gj >= Ndim) continue;
                float v = acc[mi][ni][r];
                if (bs) v += bs[gj];
                if (EPI == 1) v = gelu_exact(v);
                size_t cidx = cbase + (size_t)gi * ldc + gj;
                if (OUT == 0) ((float*)C)[cidx] = v;
                else ((bf16*)C)[cidx] = __float2bfloat16(v);
            }
        }
    }
}

// ---------- SWT decomposition: h = A [+ A2] (fp32) -> coeffs bf16; optional h writeback ----------
__global__ __launch_bounds__(128) void swt_dec_kernel(
    const float* __restrict__ h, const float* __restrict__ h2, float* __restrict__ hout,
    const float* __restrict__ h0f, const float* __restrict__ h1f, bf16* __restrict__ coeffs) {
    __shared__ float a[2][512];
    int b = blockIdx.y, n = blockIdx.x, t = threadIdx.x;
    size_t roff = ((size_t)b * Nn + n) * Dn;
    const float* hrow = h + roff;
#pragma unroll
    for (int u = 0; u < 4; ++u) {
        float v = hrow[t + u * 128];
        if (h2) v += h2[roff + t + u * 128];
        a[0][t + u * 128] = v;
        if (hout) hout[roff + t + u * 128] = v;
    }
    float f0[3], f1[3];
#pragma unroll
    for (int k = 0; k < 3; ++k) { f0[k] = h0f[n * 3 + k]; f1[k] = h1f[n * 3 + k]; }
    __syncthreads();
    bf16* cb = coeffs + roff * 4;
    int cur = 0;
    for (int lev = 0; lev < 3; ++lev) {
        int dil = 1 << lev;
        int pl = 2 * dil - (3 * dil) / 2; // 1,1,2
#pragma unroll
        for (int u = 0; u < 4; ++u) {
            int d = t + u * 128;
            float dv = 0.f, av = 0.f;
#pragma unroll
            for (int k = 0; k < 3; ++k) {
                int idx = (d + k * dil - pl) & 511;
                float xv = a[cur][idx];
                dv += f1[k] * xv;
                av += f0[k] * xv;
            }
            cb[(size_t)(3 - lev) * Dn + d] = __float2bfloat16(dv);
            a[cur ^ 1][d] = av;
        }
        __syncthreads();
        cur ^= 1;
    }
#pragma unroll
    for (int u = 0; u < 4; ++u) cb[t + u * 128] = __float2bfloat16(a[cur][t + u * 128]);
}

// ---------- SWT reconstruction: attn(b,m,n,:) bf16 -> rec(b,n,:) bf16 ----------
__global__ __launch_bounds__(128) void swt_rec_kernel(
    const bf16* __restrict__ attn, const float* __restrict__ g0f,
    const float* __restrict__ g1f, bf16* __restrict__ rec) {
    __shared__ float a[2][512];
    __shared__ float det[512];
    int b = blockIdx.y, n = blockIdx.x, t = threadIdx.x;
    const bf16* base = attn + ((size_t)(b * 4) * Nn + n) * Dn;
#pragma unroll
    for (int u = 0; u < 4; ++u) a[0][t + u * 128] = __bfloat162float(base[t + u * 128]);
    float w0[3], w1[3];
#pragma unroll
    for (int k = 0; k < 3; ++k) { w0[k] = g0f[n * 3 + k]; w1[k] = g1f[n * 3 + k]; }
    int cur = 0;
    for (int i = 0; i < 3; ++i) {
        int dil = 4 >> i;
        int pl = (3 * dil) / 2; // 6,3,1
        const bf16* drow = base + (size_t)(1 + i) * Nn * Dn;
#pragma unroll
        for (int u = 0; u < 4; ++u) det[t + u * 128] = __bfloat162float(drow[t + u * 128]);
        __syncthreads();
#pragma unroll
        for (int u = 0; u < 4; ++u) {
            int d = t + u * 128;
            float s = 0.f;
#pragma unroll
            for (int k = 0; k < 3; ++k) {
                int idx = (d + k * dil - pl) & 511;
                s += w0[k] * a[cur][idx] + w1[k] * det[idx];
            }
            a[cur ^ 1][d] = s * 0.5f;
        }
        __syncthreads();
        cur ^= 1;
    }
    bf16* out = rec + ((size_t)b * Nn + n) * Dn;
#pragma unroll
    for (int u = 0; u < 4; ++u) out[t + u * 128] = __float2bfloat16(a[cur][t + u * 128]);
}

// ---------- fused transpose-convert for QK: (b,n,m,[qk]e) -> (qk,b,m,e,n-pad) ----------
__global__ void tconv2_kernel(const bf16* __restrict__ QK, bf16* __restrict__ QtKt) {
    __shared__ bf16 tile[32][33];
    int zz = blockIdx.z;           // 0..127
    int qk = zz >> 6, bm = zz & 63;
    int b = bm >> 2, m = bm & 3;
    int e0 = blockIdx.x * 32, n0 = blockIdx.y * 32;
    int tx = threadIdx.x, ty = threadIdx.y; // 32 x 8
    const bf16* ib = QK + (size_t)b * Nn * 4096 + (size_t)m * 1024 + (size_t)qk * 512;
    bf16* ob = QtKt + (size_t)qk * 64 * 512 * KP + (size_t)bm * 512 * KP;
#pragma unroll
    for (int u = 0; u < 4; ++u) {
        int n = n0 + ty + u * 8;
        bf16 v = __float2bfloat16(0.f);
        if (n < Nn) v = ib[(size_t)n * 4096 + e0 + tx];
        tile[ty + u * 8][tx] = v;
    }
    __syncthreads();
#pragma unroll
    for (int u = 0; u < 4; ++u) {
        int e = e0 + ty + u * 8;
        int n = n0 + tx;
        if (n < KP) ob[(size_t)e * KP + n] = tile[tx][ty + u * 8];
    }
}

// ---------- column sum-sq from transposed QtKt rows (contiguous) ----------
__global__ __launch_bounds__(256) void colsq_t_kernel(const bf16* __restrict__ QtKt,
                                                      float* __restrict__ outv) {
    int wave = threadIdx.x >> 6, lane = threadIdx.x & 63;
    size_t row = (size_t)blockIdx.x * 4 + wave;   // 0..65535
    const bf16* p = QtKt + row * KP;
    float s = 0.f;
#pragma unroll
    for (int j = 0; j < 6; ++j) {
        int idx = lane + j * 64;
        if (idx < KP) { float v = __bfloat162float(p[idx]); s += v * v; }
    }
#pragma unroll
    for (int m = 1; m < 64; m <<= 1) s += __shfl_xor(s, m);
    if (lane == 0) outv[row] = s;
}

// ---------- geometric scores + softmax, wave-per-row, in place ----------
__global__ __launch_bounds__(256) void wedge_softmax_kernel(
    bf16* __restrict__ Smat, const float* __restrict__ qn2, const float* __restrict__ kn2) {
    int wave = threadIdx.x >> 6, lane = threadIdx.x & 63;
    int rowid = blockIdx.x * 4 + wave;            // 0..32767
    int bm = rowid >> 9, l = rowid & 511;
    bf16* row = Smat + (size_t)rowid * 512;
    const float* kn = kn2 + (size_t)bm * 512;
    float q2 = qn2[(size_t)bm * 512 + l];
    const float scale = rsqrtf(321.0f);
    bf16x8 dv = *reinterpret_cast<const bf16x8*>(row + lane * 8);
    float kk[8];
    *reinterpret_cast<float4*>(&kk[0]) = *reinterpret_cast<const float4*>(kn + lane * 8);
    *reinterpret_cast<float4*>(&kk[4]) = *reinterpret_cast<const float4*>(kn + lane * 8 + 4);
    float sc[8];
    float mx = -1e30f;
#pragma unroll
    for (int j = 0; j < 8; ++j) {
        float d = (float)dv[j];
        float w = sqrtf(fmaxf(q2 * kk[j] - d * d, 0.f) + 1e-8f);
        sc[j] = (0.7f * d + 0.3f * w) * scale;
        mx = fmaxf(mx, sc[j]);
    }
#pragma unroll
    for (int m = 1; m < 64; m <<= 1) mx = fmaxf(mx, __shfl_xor(mx, m));
    float sum = 0.f;
#pragma unroll
    for (int j = 0; j < 8; ++j) { sc[j] = expf(sc[j] - mx); sum += sc[j]; }
#pragma unroll
    for (int m = 1; m < 64; m <<= 1) sum += __shfl_xor(sum, m);
    float inv = 1.0f / sum;
    bf16x8 o;
#pragma unroll
    for (int j = 0; j < 8; ++j) o[j] = (__bf16)(sc[j] * inv);
    *reinterpret_cast<bf16x8*>(row + lane * 8) = o;
}

// ---------- LayerNorm, wave-per-row (grid = R/4, block 256) ----------
__global__ __launch_bounds__(256) void ln_kernel(
    const float* __restrict__ A, const float* __restrict__ R, const float* __restrict__ R2,
    const float* __restrict__ g, const float* __restrict__ bb,
    float* __restrict__ outf, bf16* __restrict__ outb) {
    int wave = threadIdx.x >> 6, lane = threadIdx.x & 63;
    size_t r = (size_t)blockIdx.x * 4 + wave;
    const float* ra = A + r * Dn + lane * 8;
    float x[8];
    *reinterpret_cast<float4*>(&x[0]) = *reinterpret_cast<const float4*>(ra);
    *reinterpret_cast<float4*>(&x[4]) = *reinterpret_cast<const float4*>(ra + 4);
    if (R) {
        const float* rr = R + r * Dn + lane * 8;
        float y[8];
        *reinterpret_cast<float4*>(&y[0]) = *reinterpret_cast<const float4*>(rr);
        *reinterpret_cast<float4*>(&y[4]) = *reinterpret_cast<const float4*>(rr + 4);
#pragma unroll
        for (int j = 0; j < 8; ++j) x[j] += y[j];
    }
    if (R2) {
        const float* rr = R2 + r * Dn + lane * 8;
        float y[8];
        *reinterpret_cast<float4*>(&y[0]) = *reinterpret_cast<const float4*>(rr);
        *reinterpret_cast<float4*>(&y[4]) = *reinterpret_cast<const float4*>(rr + 4);
#pragma unroll
        for (int j = 0; j < 8; ++j) x[j] += y[j];
    }
    float s = 0.f, s2 = 0.f;
#pragma unroll
    for (int j = 0; j < 8; ++j) { s += x[j]; s2 += x[j] * x[j]; }
#pragma unroll
    for (int m = 1; m < 64; m <<= 1) { s += __shfl_xor(s, m); s2 += __shfl_xor(s2, m); }
    float mean = s * (1.0f / Dn);
    float var = s2 * (1.0f / Dn) - mean * mean;
    float inv = rsqrtf(var + 1e-5f);
#pragma unroll
    for (int j = 0; j < 8; ++j) {
        int d = lane * 8 + j;
        float v = (x[j] - mean) * inv * g[d] + bb[d];
        if (outf) outf[r * Dn + d] = v;
        if (outb) outb[r * Dn + d] = __float2bfloat16(v);
    }
}

// ---------- dec[b,p,n] = (sum of 4 split-K partials)*sd + mu ----------
__global__ void out_scale_kernel(const float* __restrict__ ptmp,
                                 const float* __restrict__ means,
                                 const float* __restrict__ stdev, float* __restrict__ dec) {
    int idx = blockIdx.x * 256 + threadIdx.x;
    if (idx >= Bn * Pn * Nn) return;
    int n = idx % Nn;
    int bp = idx / Nn;
    int p = bp % Pn;
    int b = bp / Pn;
    const size_t PS = (size_t)Bn * Nn * Pn;
    size_t base = ((size_t)b * Nn + n) * Pn + p;
    float v = ptmp[base] + ptmp[base + PS] + ptmp[base + 2 * PS] + ptmp[base + 3 * PS];
    dec[idx] = v * stdev[b * Nn + n] + means[b * Nn + n];
}

extern "C" void kernel_launch(void* const* d_in, const int* in_sizes, int n_in,
                              void* d_out, int out_size, void* d_ws, size_t ws_size,
                              hipStream_t stream) {
    const float* x_enc = (const float*)d_in[0];
    const float* emb_W = (const float*)d_in[1];
    const float* emb_b = (const float*)d_in[2];
    const float* h0 = (const float*)d_in[3];
    const float* h1 = (const float*)d_in[4];
    const float* g0 = (const float*)d_in[5];
    const float* g1 = (const float*)d_in[6];
    const float* Wq = (const float*)d_in[7];
    const float* bq = (const float*)d_in[8];
    const float* Wk = (const float*)d_in[9];
    const float* bk = (const float*)d_in[10];
    const float* Wv = (const float*)d_in[11];
    const float* bv = (const float*)d_in[12];
    const float* Wo = (const float*)d_in[13];
    const float* bo = (const float*)d_in[14];
    const float* W1 = (const float*)d_in[15];
    const float* b1 = (const float*)d_in[16];
    const float* W2 = (const float*)d_in[17];
    const float* b2 = (const float*)d_in[18];
    const float* ln1_g = (const float*)d_in[19];
    const float* ln1_b = (const float*)d_in[20];
    const float* ln2_g = (const float*)d_in[21];
    const float* ln2_b = (const float*)d_in[22];
    const float* lnf_g = (const float*)d_in[23];
    const float* lnf_b = (const float*)d_in[24];
    const float* proj_W = (const float*)d_in[25];
    const float* proj_b = (const float*)d_in[26];

    float* dec = (float*)d_out;
    float* means = dec + (size_t)Bn * Pn * Nn;
    float* stdev = means + (size_t)Bn * Nn;

    // ---- workspace carve (~154 MB, proven watermark) ----
    char* p = (char*)d_ws;
    auto alloc = [&](size_t bytes) { char* r = p; p += (bytes + 255) & ~(size_t)255; return r; };
    const size_t RD = (size_t)Bn * Nn * Dn;        // 2,629,632 elements
    const size_t RQ4 = RD * 4;                     // 10,518,528

    bf16* embWb = (bf16*)alloc(262144 * 2);
    bf16* Wqkb = (bf16*)alloc(2 * 524288 * 2);
    bf16* Wvb = (bf16*)alloc(2 * 262144 * 2);
    bf16* Wob = (bf16*)alloc(2 * 262144 * 2);
    bf16* W1b = (bf16*)alloc(2 * 1048576 * 2);
    bf16* W2b = (bf16*)alloc(2 * 1048576 * 2);
    bf16* projWb = (bf16*)alloc(49152 * 2);
    float* bqk = (float*)alloc(2048 * 4);

    float* hbuf = (float*)alloc(RD * 4);
    char* regC = alloc(RQ4 * 2);                     // coeffs_b | attn_b
    char* regQ = alloc(RQ4 * 2);                     // QK0b(head) | Smat(head) | recb,x1b | ptmp
    char* regK = alloc(RQ4 * 2);                     // QK0b(tail) | Smat(tail)
    char* regV = alloc(RQ4 * 2);                     // V0b | yb
    char* regT = alloc((size_t)2 * 64 * 512 * KP * 2); // xT_b | QtKt | x1,tmp(x2),hfb
    float* qn2 = (float*)alloc((size_t)2 * 64 * 512 * 4);
    float* kn2 = qn2 + 32768;

    bf16* coeffs_b = (bf16*)regC;
    bf16* attn_b = (bf16*)regC;
    bf16* QK0b = (bf16*)regQ;
    bf16* Smat = (bf16*)regQ;
    bf16* recb = (bf16*)regQ;
    bf16* x1b = (bf16*)(regQ + RD * 2);
    float* ptmp = (float*)regQ;
    bf16* V0b = (bf16*)regV;
    bf16* yb = (bf16*)regV;
    bf16* QtKt = (bf16*)regT;
    bf16* Qt = QtKt;
    bf16* Kt = QtKt + (size_t)64 * 512 * KP;
    bf16* xT_b = (bf16*)regT;
    float* x1 = (float*)regT;
    float* tmp = (float*)(regT + RD * 4);
    bf16* hfb = (bf16*)(regT + RD * 12);

    const int R = Bn * Nn;   // 5136
    const int RQr = R * 4;   // 20544
    const long sbm = (long)4 * Nn * 512;
    const long sS = (long)512 * 512;
    const long sTq = (long)512 * KP;
    const long sTb = 4 * sTq;

    CvtPack cp;
    int ci = 0;
    auto addcvt = [&](const float* s, bf16* d, int n) { cp.src[ci] = s; cp.dst[ci] = d; cp.cnt[ci] = n; ++ci; };
    addcvt(emb_W, embWb, 262144);
    for (int l = 0; l < 2; ++l) {
        addcvt(Wq + (size_t)l * 262144, Wqkb + (size_t)l * 524288, 262144);
        addcvt(Wk + (size_t)l * 262144, Wqkb + (size_t)l * 524288 + 262144, 262144);
        addcvt(Wv + (size_t)l * 262144, Wvb + (size_t)l * 262144, 262144);
        addcvt(Wo + (size_t)l * 262144, Wob + (size_t)l * 262144, 262144);
        addcvt(W1 + (size_t)l * 1048576, W1b + (size_t)l * 1048576, 1048576);
        addcvt(W2 + (size_t)l * 1048576, W2b + (size_t)l * 1048576, 1048576);
    }
    addcvt(proj_W, projWb, 49152);
    cvt_all_kernel<<<dim3(1048576 / 4 / 256, 14), 256, 0, stream>>>(cp);
    bias_pack_kernel<<<8, 256, 0, stream>>>(bq, bk, bqk);

    stats_kernel<<<dim3((Nn + 255) / 256, Bn), 256, 0, stream>>>(x_enc, means, stdev);
    transpose_norm_kernel<<<dim3(Sn / 32, (Nn + 31) / 32, Bn), dim3(32, 8), 0, stream>>>(
        x_enc, means, stdev, xT_b);

    // embed split-K=2 -> tmp partials (summed in layer-0 swt_dec)
    mm_kernel<0, 0><<<dim3(4, (R + 127) / 128, 2), 256, 0, stream>>>(
        xT_b, embWb, emb_b, tmp, R, Dn, 256, Sn, Sn, Dn,
        256, 0, 256, 0, (long)RD, 0, 2);

    for (int l = 0; l < 2; ++l) {
        const float* h0l = h0 + (size_t)l * Nn * 3;
        const float* h1l = h1 + (size_t)l * Nn * 3;
        const float* g0l = g0 + (size_t)l * Nn * 3;
        const float* g1l = g1 + (size_t)l * Nn * 3;

        if (l == 0)
            swt_dec_kernel<<<dim3(Nn, Bn), 128, 0, stream>>>(tmp, tmp + RD, hbuf, h0l, h1l, coeffs_b);
        else
            swt_dec_kernel<<<dim3(Nn, Bn), 128, 0, stream>>>(hbuf, nullptr, nullptr, h0l, h1l, coeffs_b);

        // fused QK: rows (b,n,m) x 1024 -> QK0b (1288 blocks, MT=128)
        mm_kernel<1, 0><<<dim3(8, (RQr + 127) / 128, 1), 256, 0, stream>>>(
            coeffs_b, Wqkb + (size_t)l * 524288, bqk + (size_t)l * 1024, QK0b,
            RQr, 1024, Dn, Dn, Dn, 1024, 0, 0, 0, 0, 0, 0, 1);
        // V: rows (b,n,m) x 512 -> V0b
        mm_kernel<1, 0><<<dim3(4, (RQr + 127) / 128, 1), 256, 0, stream>>>(
            coeffs_b, Wvb + (size_t)l * 262144, bv + (size_t)l * Dn, V0b,
            RQr, Dn, Dn, Dn, Dn, Dn, 0, 0, 0, 0, 0, 0, 1);

        tconv2_kernel<<<dim3(16, 11, 128), dim3(32, 8), 0, stream>>>(QK0b, QtKt);
        colsq_t_kernel<<<16384, 256, 0, stream>>>(QtKt, qn2);

        // dot[bm,l,s] = sum_n Qt[l,n]*Kt[s,n] -> bf16 Smat (QK0b dead now)
        mm_kernel<1, 0><<<dim3(4, 4, 64), 256, 0, stream>>>(
            Qt, Kt, nullptr, Smat, 512, 512, KP, KP, KP, 512,
            sTq, sTb, sTq, sTb, sS, 4 * sS, 4);

        wedge_softmax_kernel<<<8192, 256, 0, stream>>>(Smat, qn2, kn2);

        // attn[b,m,n,l] = sum_s V0b[(b,n,m),s] * Smat[bm,l,s] -> bf16
        mm_kernel<1, 0><<<dim3(4, (Nn + 127) / 128, 64), 256, 0, stream>>>(
            V0b, Smat, nullptr, attn_b, Nn, 512, 512, 2048, 512, 512,
            512, sbm, sS, 4 * sS, (long)Nn * 512, (long)4 * Nn * 512, 4);

        // Smat dead; recb overwrites its head
        swt_rec_kernel<<<dim3(Nn, Bn), 128, 0, stream>>>(attn_b, g0l, g1l, recb);

        // Wo split-K=2 -> tmp partials
        mm_kernel<0, 0><<<dim3(4, (R + 127) / 128, 2), 256, 0, stream>>>(
            recb, Wob + (size_t)l * 262144, bo + (size_t)l * Dn, tmp,
            R, Dn, 256, Dn, Dn, Dn, 256, 0, 256, 0, (long)RD, 0, 2);
        ln_kernel<<<R / 4, 256, 0, stream>>>(hbuf, tmp, tmp + RD, ln1_g + (size_t)l * Dn,
                                             ln1_b + (size_t)l * Dn, x1, x1b);

        // FFN1 (gelu, bf16 out)
        mm_kernel<1, 1><<<dim3(16, (R + 127) / 128, 1), 256, 0, stream>>>(
            x1b, W1b + (size_t)l * 1048576, b1 + (size_t)l * DFn, yb,
            R, DFn, Dn, Dn, Dn, DFn, 0, 0, 0, 0, 0, 0, 1);
        // FFN2 split-K=2 -> tmp partials
        mm_kernel<0, 0><<<dim3(4, (R + 127) / 128, 2), 256, 0, stream>>>(
            yb, W2b + (size_t)l * 1048576, b2 + (size_t)l * Dn, tmp,
            R, Dn, 1024, DFn, DFn, Dn, 1024, 0, 1024, 0, (long)RD, 0, 2);
        ln_kernel<<<R / 4, 256, 0, stream>>>(x1, tmp, tmp + RD, ln2_g + (size_t)l * Dn,
                                             ln2_b + (size_t)l * Dn, hbuf, nullptr);
    }

    ln_kernel<<<R / 4, 256, 0, stream>>>(hbuf, nullptr, nullptr, lnf_g, lnf_b, nullptr, hfb);
    // proj split-K=4 -> ptmp partials
    mm_kernel<0, 0><<<dim3(1, (R + 127) / 128, 4), 256, 0, stream>>>(
        hfb, projWb, proj_b, ptmp, R, Pn, 128, Dn, Dn, Pn,
        128, 0, 128, 0, (long)R * Pn, 0, 4);
    out_scale_kernel<<<(Bn * Pn * Nn + 255) / 256, 256, 0, stream>>>(ptmp, means, stdev, dec);
}